// Round 2
// baseline (286.965 us; speedup 1.0000x reference)
//
#include <hip/hip_runtime.h>

// LinkPrediction: per-edge 2-layer MLP routed by edge type (MoE-style).
// outputs: [0..N_EDGES) = scores, [N_EDGES..) = copy of rgcn_emb.
//
// R4 theory: score16 was only 85us of 278 -> ~190us in prep chain + gaps.
//  (1) prep_k fuses hist + W1-convert + {emb copy, f16 convert} in ONE pass
//      over emb (saves a 102MB re-read; NT load/store on the fp32 stream so
//      the 51.2MB f16 table stays LLC-resident for the gathers).
//  (2) scatter_k = proven two-pass reservation, standalone (tiny).
//  (3) score16_ns_k: no copy duty, exact 1571-block grid (1 occupancy round),
//      explicit A/B double-buffered 128B gather chunks to hide latency.
// R5: fix — __builtin_nontemporal_* rejects HIP float4 (class type); use a
//      native ext_vector_type(4) float for the NT-streamed pointers.

typedef _Float16 h2 __attribute__((ext_vector_type(2)));
typedef float    f4 __attribute__((ext_vector_type(4)));

constexpr int N_NODES = 200000;
constexpr int N_EDGES = 400000;
constexpr int EMB_DIM = 128;
constexpr int HID     = 24;
constexpr int N_TYPES = 8;
constexpr int BLK     = 256;

constexpr int MAX_PAD      = N_EDGES + N_TYPES * (BLK - 1);
constexpr int SCORE_BLOCKS = (MAX_PAD + BLK - 1) / BLK;        // 1571
constexpr int SC_BLOCKS    = 128;
constexpr int SC_CH        = (N_EDGES + SC_BLOCKS - 1) / SC_BLOCKS;  // 3125

constexpr int PREP_HIST   = 64;    // vectorized histogram blocks
constexpr int PREP_W1     = 16;    // W1 fp32->h2 blocks
constexpr int PREP_CONV   = 1968;  // fused copy+convert blocks
constexpr int PREP_BLOCKS = PREP_HIST + PREP_W1 + PREP_CONV;   // 2048

// ws layout: [0..8) counts, [8..16) fill, [16..16+MAX_PAD) sorted,
// then (256B-aligned) emb16 (N_NODES*128 f16 = 51.2MB), then w16 (98.3KB).
constexpr size_t SORT_BYTES  = (size_t)(16 + MAX_PAD) * sizeof(int);
constexpr size_t EMB16_OFF   = (SORT_BYTES + 255) & ~(size_t)255;
constexpr size_t EMB16_BYTES = (size_t)N_NODES * EMB_DIM * 2;
constexpr size_t W16_OFF     = EMB16_OFF + EMB16_BYTES;
constexpr size_t W16_BYTES   = (size_t)N_TYPES * 128 * HID * 4;  // h2 per (kp,j)
constexpr size_t NEED16      = W16_OFF + W16_BYTES;

__device__ __forceinline__ float fdot2f(h2 a, h2 b, float c) {
#if __has_builtin(__builtin_amdgcn_fdot2)
    return __builtin_amdgcn_fdot2(a, b, c, false);
#else
    return c + (float)a[0] * (float)b[0] + (float)a[1] * (float)b[1];
#endif
}

// ---------- prep: hist (64 blk) | W1 convert (16 blk) | copy+f16 (1968 blk) ----------
__global__ __launch_bounds__(BLK) void prep_k(
        const int* __restrict__ etype, int* __restrict__ counts,
        const float* __restrict__ emb, float* __restrict__ out,
        int2* __restrict__ emb16, const float* __restrict__ W1,
        h2* __restrict__ w16) {
    int b = blockIdx.x;
    if (b < PREP_HIST) {
        __shared__ int lc[N_TYPES];
        if (threadIdx.x < N_TYPES) lc[threadIdx.x] = 0;
        __syncthreads();
        const int4* et4 = (const int4*)etype;          // N_EDGES % 4 == 0
        for (int g = b * BLK + threadIdx.x; g < N_EDGES / 4; g += PREP_HIST * BLK) {
            int4 v = et4[g];
            atomicAdd(&lc[v.x], 1); atomicAdd(&lc[v.y], 1);
            atomicAdd(&lc[v.z], 1); atomicAdd(&lc[v.w], 1);
        }
        __syncthreads();
        if (threadIdx.x < N_TYPES) {
            int v = lc[threadIdx.x];
            if (v) atomicAdd(&counts[threadIdx.x], v);
        }
    } else if (b < PREP_HIST + PREP_W1) {
        int cb = b - PREP_HIST;
        for (int p = cb * BLK + threadIdx.x; p < N_TYPES * 128 * HID; p += PREP_W1 * BLK) {
            int t   = p / (128 * HID);
            int rem = p - t * 128 * HID;
            int kp  = rem / HID, j = rem - kp * HID;
            h2 v;
            v[0] = (_Float16)W1[(t * 256 + 2 * kp)     * HID + j];
            v[1] = (_Float16)W1[(t * 256 + 2 * kp + 1) * HID + j];
            w16[p] = v;
        }
    } else {
        int cb = b - PREP_HIST - PREP_W1;
        const f4* in4 = (const f4*)emb;
        f4* o4 = (f4*)(out + N_EDGES);
        const int n4 = N_NODES * EMB_DIM / 4;          // 6.4M
        for (int i = cb * BLK + threadIdx.x; i < n4; i += PREP_CONV * BLK) {
            f4 a = __builtin_nontemporal_load(&in4[i]);   // don't cache fp32 in LLC
            __builtin_nontemporal_store(a, &o4[i]);       // copy never re-read
            union { int2 v; h2 h[2]; } u;
            u.h[0] = h2{(_Float16)a.x, (_Float16)a.y};
            u.h[1] = h2{(_Float16)a.z, (_Float16)a.w};
            emb16[i] = u.v;                               // normal store: keep in LLC
        }
    }
}

// ---------- scatter: two-pass reservation (proven R3 structure) ----------
__global__ __launch_bounds__(BLK) void scatter_k(
        const int* __restrict__ etype, int* __restrict__ counts,
        int* __restrict__ sorted) {
    __shared__ int lc[N_TYPES], base[N_TYPES];
    int b = blockIdx.x;
    if (threadIdx.x < N_TYPES) lc[threadIdx.x] = 0;
    __syncthreads();
    int e0 = b * SC_CH, e1 = min(e0 + SC_CH, N_EDGES);
    for (int e = e0 + threadIdx.x; e < e1; e += BLK)
        atomicAdd(&lc[etype[e]], 1);
    __syncthreads();
    if (threadIdx.x < N_TYPES)
        base[threadIdx.x] = atomicAdd(&counts[8 + threadIdx.x], lc[threadIdx.x]);
    __syncthreads();
    if (threadIdx.x < N_TYPES) lc[threadIdx.x] = 0;
    __syncthreads();
    int poff[N_TYPES];
    int off = 0;
#pragma unroll
    for (int t = 0; t < N_TYPES; ++t) {
        poff[t] = off;
        off += ((counts[t] + BLK - 1) / BLK) * BLK;
    }
    for (int e = e0 + threadIdx.x; e < e1; e += BLK) {
        int t = etype[e];
        int r = atomicAdd(&lc[t], 1);
        sorted[poff[t] + base[t] + r] = e;
    }
}

// ---------- score (f16, no copy duty, double-buffered gather) ----------
__device__ __forceinline__ void compute_chunk(const int4* __restrict__ r,
                                              const h2* __restrict__ wrow,
                                              float acc[HID]) {
    const h2* hp = (const h2*)r;   // 32 h2 pairs in regs
#pragma unroll
    for (int kp = 0; kp < 32; ++kp) {
#pragma unroll
        for (int j = 0; j < HID; ++j)
            acc[j] = fdot2f(hp[kp], wrow[kp * HID + j], acc[j]);
    }
}

__global__ __launch_bounds__(BLK) void score16_ns_k(
        const unsigned short* __restrict__ emb16u,
        const int* __restrict__ srci, const int* __restrict__ dsti,
        const int* __restrict__ counts, const int* __restrict__ sorted,
        const h2* __restrict__ w16, const float* __restrict__ b1,
        const float* __restrict__ W2, const float* __restrict__ b2,
        float* __restrict__ out) {
    int poff[N_TYPES];
    int off = 0;
#pragma unroll
    for (int t = 0; t < N_TYPES; ++t) {
        poff[t] = off;
        off += ((counts[t] + BLK - 1) / BLK) * BLK;
    }
    int slot0 = blockIdx.x * BLK;
    if (slot0 >= off) return;
    int t = 0;
#pragma unroll
    for (int i = 1; i < N_TYPES; ++i)
        if (slot0 >= poff[i]) t = i;
    t = __builtin_amdgcn_readfirstlane(t);   // wave-uniform type -> scalar W loads
    int cnt = counts[t];
    int local = slot0 - poff[t] + (int)threadIdx.x;
    if (local >= cnt) return;
    int e = sorted[slot0 + threadIdx.x];
    int s = srci[e], d = dsti[e];

    float acc[HID];
#pragma unroll
    for (int j = 0; j < HID; ++j) acc[j] = b1[t * HID + j];
    const h2* wt = w16 + (size_t)t * 128 * HID;
    const int4* x0 = (const int4*)(emb16u + (size_t)s * EMB_DIM);
    const int4* x1 = (const int4*)(emb16u + (size_t)d * EMB_DIM);

    // A/B double buffer: next 128B chunk in flight while current computes.
    int4 A[8], B[8];
#pragma unroll
    for (int k = 0; k < 8; ++k) A[k] = x0[k];
#pragma unroll
    for (int k = 0; k < 8; ++k) B[k] = x0[8 + k];
    compute_chunk(A, wt + 0 * 32 * HID, acc);
#pragma unroll
    for (int k = 0; k < 8; ++k) A[k] = x1[k];
    compute_chunk(B, wt + 1 * 32 * HID, acc);
#pragma unroll
    for (int k = 0; k < 8; ++k) B[k] = x1[8 + k];
    compute_chunk(A, wt + 2 * 32 * HID, acc);
    compute_chunk(B, wt + 3 * 32 * HID, acc);

    float sc = b2[t];
#pragma unroll
    for (int j = 0; j < HID; ++j) {
        float h = acc[j];
        h = (h > 0.f) ? h : 0.01f * h;       // LeakyReLU(0.01)
        sc = fmaf(h, W2[t * HID + j], sc);
    }
    out[e] = sc;
}

// ---------- fallback (ws too small): fp32, unsorted, correctness only ----------
__global__ __launch_bounds__(BLK) void fallback_k(
        const float* __restrict__ emb,
        const int* __restrict__ srci, const int* __restrict__ dsti,
        const int* __restrict__ etype,
        const float* __restrict__ W1, const float* __restrict__ b1,
        const float* __restrict__ W2, const float* __restrict__ b2,
        float* __restrict__ out) {
    long long i0 = (long long)blockIdx.x * BLK + threadIdx.x;
    const float4* s4 = (const float4*)emb;
    float4* o4 = (float4*)(out + N_EDGES);
    const long long n4 = (long long)N_NODES * EMB_DIM / 4;
    for (long long i = i0; i < n4; i += (long long)gridDim.x * BLK)
        o4[i] = s4[i];
    for (int e = (int)i0; e < N_EDGES; e += gridDim.x * BLK) {
        int t = etype[e];
        int s = srci[e], d = dsti[e];
        float acc[HID];
#pragma unroll
        for (int j = 0; j < HID; ++j) acc[j] = b1[t * HID + j];
        const float* w = W1 + (size_t)t * 2 * EMB_DIM * HID;
        for (int k = 0; k < EMB_DIM; ++k) {
            float x = emb[(size_t)s * EMB_DIM + k];
#pragma unroll
            for (int j = 0; j < HID; ++j) acc[j] = fmaf(x, w[k * HID + j], acc[j]);
        }
        for (int k = 0; k < EMB_DIM; ++k) {
            float x = emb[(size_t)d * EMB_DIM + k];
#pragma unroll
            for (int j = 0; j < HID; ++j) acc[j] = fmaf(x, w[(EMB_DIM + k) * HID + j], acc[j]);
        }
        float sc = b2[t];
#pragma unroll
        for (int j = 0; j < HID; ++j) {
            float h = acc[j];
            h = (h > 0.f) ? h : 0.01f * h;
            sc = fmaf(h, W2[t * HID + j], sc);
        }
        out[e] = sc;
    }
}

extern "C" void kernel_launch(void* const* d_in, const int* in_sizes, int n_in,
                              void* d_out, int out_size, void* d_ws, size_t ws_size,
                              hipStream_t stream) {
    const float* emb   = (const float*)d_in[0];
    const int*   eidx  = (const int*)d_in[1];
    const int*   etype = (const int*)d_in[2];
    const float* W1    = (const float*)d_in[3];
    const float* b1    = (const float*)d_in[4];
    const float* W2    = (const float*)d_in[5];
    const float* b2    = (const float*)d_in[6];
    float* out = (float*)d_out;
    const int* srci = eidx;
    const int* dsti = eidx + N_EDGES;

    if (ws_size >= NEED16) {
        int* counts = (int*)d_ws;            // [0..8) counts, [8..16) fill
        int* sorted = counts + 16;
        int2* emb16 = (int2*)((char*)d_ws + EMB16_OFF);
        h2*   w16   = (h2*)((char*)d_ws + W16_OFF);
        (void)hipMemsetAsync(counts, 0, 16 * sizeof(int), stream);
        prep_k<<<PREP_BLOCKS, BLK, 0, stream>>>(etype, counts, emb, out, emb16, W1, w16);
        scatter_k<<<SC_BLOCKS, BLK, 0, stream>>>(etype, counts, sorted);
        score16_ns_k<<<SCORE_BLOCKS, BLK, 0, stream>>>(
            (const unsigned short*)emb16, srci, dsti, counts, sorted,
            w16, b1, W2, b2, out);
    } else {
        fallback_k<<<2048, BLK, 0, stream>>>(emb, srci, dsti, etype, W1, b1, W2, b2, out);
    }
}